// Round 4
// baseline (360.910 us; speedup 1.0000x reference)
//
#include <hip/hip_runtime.h>
#include <math.h>

typedef __bf16  bf16x8 __attribute__((ext_vector_type(8)));
typedef float   f32x4  __attribute__((ext_vector_type(4)));

// async global->LDS, 16B per lane. Pass per-lane dest (= base + lane*16).
#define GLD_LDS16(dst, src)                                                      \
    __builtin_amdgcn_global_load_lds(                                            \
        (const __attribute__((address_space(1))) unsigned int*)(src),            \
        (__attribute__((address_space(3))) unsigned int*)(dst), 16, 0, 0)

// ---------------------------------------------------------------------------
// Kernel T+A: x[b,ci,h,w] fp32 -> xT[b,h,w,ci] bf16, fused global-avg-pool
// (atomicAdd of per-row partial sums; pooled must be memset to 0 first).
// block = (h, b); wave handles 8 ci x 64 w per iter.
// ---------------------------------------------------------------------------
__global__ __launch_bounds__(256) void transpose_pool_kernel(
    const float* __restrict__ x, __bf16* __restrict__ xT,
    float* __restrict__ pooled) {
    int h = blockIdx.x, b = blockIdx.y;
    int lane = threadIdx.x & 63, wv = threadIdx.x >> 6;
#pragma unroll
    for (int i = 0; i < 8; i++) {
        int cq = i * 4 + wv;                       // ci octet 0..31
        const float* src = x + (((size_t)(b * 256 + cq * 8) * 64 + h) * 64 + lane);
        bf16x8 o;
#pragma unroll
        for (int j = 0; j < 8; j++) {
            float v = src[(size_t)j * 4096];
            o[j] = (__bf16)v;
            // reduce over the 64 w-lanes of this row
#pragma unroll
            for (int off = 32; off > 0; off >>= 1) v += __shfl_down(v, off, 64);
            if (lane == 0)
                atomicAdd(&pooled[b * 256 + cq * 8 + j], v * (1.f / 4096.f));
        }
        *(bf16x8*)(xT + (((size_t)(b * 64 + h) * 64 + lane) * 256 + cq * 8)) = o;
    }
}

// ---------------------------------------------------------------------------
// Kernel B: routing heads -> S[b,n,9,9] = lambda * R(theta); BN fold
// ---------------------------------------------------------------------------
__global__ __launch_bounds__(256) void routing_kernel(
    const float* __restrict__ pooled,
    const float* __restrict__ w_lambda, const float* __restrict__ w_theta,
    const float* __restrict__ bn_gamma, const float* __restrict__ bn_beta,
    const float* __restrict__ bn_mean,  const float* __restrict__ bn_var,
    float* __restrict__ S, float* __restrict__ bnscale, float* __restrict__ bnshift) {
    int t = threadIdx.x;
    if (t < 256) {
        float inv = rsqrtf(bn_var[t] + 1e-5f);
        float sc = bn_gamma[t] * inv;
        bnscale[t] = sc;
        bnshift[t] = bn_beta[t] - bn_mean[t] * sc;
    }
    if (t < 64) {
        int b = t >> 2, n = t & 3;
        float zl = 0.f, zt = 0.f;
        for (int ci = 0; ci < 256; ci++) {
            float p = pooled[b * 256 + ci];
            zl += p * w_lambda[ci * 4 + n];
            zt += p * w_theta[ci * 4 + n];
        }
        float lam = 1.f / (1.f + expf(-zl));
        float th  = 3.14159265358979323846f * (zt / (1.f + fabsf(zt)));
        float xc = cosf(th), ys = sinf(th);
        float a = xc - ys, bb = xc * ys, c = xc + ys;
        float R[9][9];
#pragma unroll
        for (int i = 0; i < 9; i++)
#pragma unroll
            for (int j = 0; j < 9; j++) R[i][j] = 0.f;
        if (th >= 0.f) {
            R[0][0] = a;       R[0][1] = 1 - a;
            R[1][1] = xc - bb; R[1][2] = bb;       R[1][4] = 1 - c + bb; R[1][5] = ys - bb;
            R[2][2] = a;       R[2][5] = 1 - a;
            R[3][0] = bb;      R[3][1] = ys - bb;  R[3][3] = xc - bb;    R[3][4] = 1 - c + bb;
            R[4][4] = 1.f;
            R[5][4] = 1 - c + bb; R[5][5] = xc - bb; R[5][7] = ys - bb;  R[5][8] = bb;
            R[6][3] = 1 - a;   R[6][6] = a;
            R[7][3] = ys - bb; R[7][4] = 1 - c + bb; R[7][6] = bb;       R[7][7] = xc - bb;
            R[8][7] = 1 - a;   R[8][8] = a;
        } else {
            R[0][0] = c;       R[0][3] = 1 - c;
            R[1][0] = -bb;     R[1][1] = xc + bb;  R[1][3] = bb - ys;    R[1][4] = 1 - a - bb;
            R[2][1] = 1 - c;   R[2][2] = c;
            R[3][3] = xc + bb; R[3][4] = 1 - a - bb; R[3][6] = -bb;      R[3][7] = bb - ys;
            R[4][4] = 1.f;
            R[5][1] = bb - ys; R[5][2] = -bb;      R[5][4] = 1 - a - bb; R[5][5] = xc + bb;
            R[6][6] = c;       R[6][7] = 1 - c;
            R[7][4] = 1 - a - bb; R[7][5] = bb - ys; R[7][7] = xc + bb;  R[7][8] = -bb;
            R[8][5] = 1 - c;   R[8][8] = c;
        }
        float* Sp = S + (b * 4 + n) * 81;
#pragma unroll
        for (int p = 0; p < 9; p++)
#pragma unroll
            for (int q = 0; q < 9; q++) Sp[p * 9 + q] = lam * R[p][q];
    }
}

// ---------------------------------------------------------------------------
// Kernel C: rotated weights  rwq[b][p][co][ci] bf16.
// ---------------------------------------------------------------------------
__global__ __launch_bounds__(256) void rotw_kernel(const float* __restrict__ weight,
                                                   const float* __restrict__ S,
                                                   __bf16* __restrict__ rwq) {
    __shared__ float wlds[4][2304];      // [n][ci*9+q]
    int co = blockIdx.x;
    int t = threadIdx.x;
#pragma unroll
    for (int n = 0; n < 4; n++) {
        const float* wp = weight + ((size_t)n * 256 + co) * 2304;
        for (int i = t; i < 2304; i += 256) wlds[n][i] = wp[i];
    }
    __syncthreads();
    int ci = t;
    float w[4][9];
#pragma unroll
    for (int n = 0; n < 4; n++)
#pragma unroll
        for (int q = 0; q < 9; q++) w[n][q] = wlds[n][ci * 9 + q];
    for (int b = 0; b < 16; b++) {
#pragma unroll
        for (int p = 0; p < 9; p++) {
            float s = 0.f;
#pragma unroll
            for (int n = 0; n < 4; n++) {
                const float* sp = S + (b * 4 + n) * 81 + p * 9;   // uniform -> s_load
#pragma unroll
                for (int q = 0; q < 9; q++) s += sp[q] * w[n][q];
            }
            rwq[(((size_t)b * 9 + p) * 256 + co) * 256 + ci] = (__bf16)s;
        }
    }
}

// ---------------------------------------------------------------------------
// Kernel D: implicit-GEMM conv + fused BN/ReLU.
// Tile: b, 64 co, 8 output rows. 4 waves; wave wv owns rows {wv, wv+4}.
// Per ci-chunk (32 ci): ONE staging phase (x: 40 units, weights: all 9 taps,
// 36 units) + 2 barriers, then 9 taps x 32 MFMA per wave.
// LDS: xs[10][4][66][8] (42240 B) + as9[9][4][66][8] (38016 B) = 80256 B
// -> 2 blocks/CU. kq stride = 1056 B (skewed 8 banks, no quad aliasing).
// ---------------------------------------------------------------------------
__global__ __launch_bounds__(256, 2) void conv_kernel(
    const __bf16* __restrict__ xT, const __bf16* __restrict__ rwq,
    const float* __restrict__ bnscale, const float* __restrict__ bnshift,
    float* __restrict__ out) {
    __shared__ __attribute__((aligned(16))) __bf16 xs[10][4][66][8];
    __shared__ __attribute__((aligned(16))) __bf16 as9[9][4][66][8];

    const int t    = threadIdx.x;
    const int lane = t & 63;
    const int wv   = t >> 6;
    const int l15  = lane & 15;
    const int kq4  = lane >> 4;

    const int h0  = blockIdx.x * 8;
    const int co0 = blockIdx.y * 64;
    const int b   = blockIdx.z;

    f32x4 acc[2][4][4];
#pragma unroll
    for (int r = 0; r < 2; r++)
#pragma unroll
        for (int m = 0; m < 4; m++)
#pragma unroll
            for (int n = 0; n < 4; n++) acc[r][m][n] = (f32x4){0.f, 0.f, 0.f, 0.f};

    const uint4 zero4 = {0u, 0u, 0u, 0u};
    // halo cols 0 and 65 (w = -1 / 64): always zero, write once
    if (t < 40) {
        int rr = t >> 2, kq = t & 3;
        *(uint4*)&xs[rr][kq][0][0]  = zero4;
        *(uint4*)&xs[rr][kq][65][0] = zero4;
    }

    for (int ci0 = 0; ci0 < 256; ci0 += 32) {
        __syncthreads();                 // prev chunk's compute done before overwrite
        // stage x: 40 units (rr 0..9, kq 0..3); 10 per wave; lane = w
#pragma unroll
        for (int u = wv * 10; u < wv * 10 + 10; u++) {
            int rr = u >> 2, kq = u & 3;
            int hh = h0 - 1 + rr;
            if (hh >= 0 && hh < 64) {
                const __bf16* src = xT + (((size_t)(b * 64 + hh) * 64 + lane) * 256 + ci0 + kq * 8);
                GLD_LDS16(&xs[rr][kq][1 + lane][0], src);
            } else {
                *(uint4*)&xs[rr][kq][1 + lane][0] = zero4;
            }
        }
        // stage weights, all 9 taps: 36 units (tap, kq); 9 per wave; lane = co
#pragma unroll
        for (int u = wv * 9; u < wv * 9 + 9; u++) {
            int tap = u >> 2, kq = u & 3;
            const __bf16* src = rwq +
                ((((size_t)b * 9 + tap) * 256 + co0 + lane) * 256 + ci0 + kq * 8);
            GLD_LDS16(&as9[tap][kq][lane][0], src);
        }
        __syncthreads();                 // drains DMA; xs + as9 ready
#pragma unroll
        for (int tap = 0; tap < 9; tap++) {
            const int dh = tap / 3, dw = tap % 3;
            bf16x8 af[4];
#pragma unroll
            for (int m = 0; m < 4; m++)
                af[m] = *(const bf16x8*)&as9[tap][kq4][m * 16 + l15][0];
#pragma unroll
            for (int r = 0; r < 2; r++) {
                const int hl = wv + r * 4;
#pragma unroll
                for (int nt = 0; nt < 4; nt++) {
                    bf16x8 bfr = *(const bf16x8*)&xs[hl + dh][kq4][nt * 16 + l15 + dw][0];
#pragma unroll
                    for (int m = 0; m < 4; m++)
                        acc[r][m][nt] = __builtin_amdgcn_mfma_f32_16x16x32_bf16(
                            af[m], bfr, acc[r][m][nt], 0, 0, 0);
                }
            }
        }
    }

    // epilogue: BN + ReLU. D layout: row(co) = kq4*4+reg, col(w) = l15
#pragma unroll
    for (int r = 0; r < 2; r++) {
        const int h = h0 + wv + r * 4;
#pragma unroll
        for (int m = 0; m < 4; m++) {
#pragma unroll
            for (int reg = 0; reg < 4; reg++) {
                int co = co0 + m * 16 + kq4 * 4 + reg;
                float sc = bnscale[co], sh = bnshift[co];
#pragma unroll
                for (int nt = 0; nt < 4; nt++) {
                    int w = nt * 16 + l15;
                    float v = acc[r][m][nt][reg] * sc + sh;
                    out[(((size_t)b * 256 + co) * 64 + h) * 64 + w] = v > 0.f ? v : 0.f;
                }
            }
        }
    }
}

// ---------------------------------------------------------------------------
extern "C" void kernel_launch(void* const* d_in, const int* in_sizes, int n_in,
                              void* d_out, int out_size, void* d_ws, size_t ws_size,
                              hipStream_t stream) {
    const float* x        = (const float*)d_in[0];
    const float* weight   = (const float*)d_in[1];
    const float* w_lambda = (const float*)d_in[2];
    const float* w_theta  = (const float*)d_in[3];
    const float* bn_gamma = (const float*)d_in[4];
    const float* bn_beta  = (const float*)d_in[5];
    const float* bn_mean  = (const float*)d_in[6];
    const float* bn_var   = (const float*)d_in[7];
    float* out = (float*)d_out;

    char* ws = (char*)d_ws;
    float*  pooled  = (float*)(ws);                     // 4096 f (atomic acc, memset 0)
    float*  S       = (float*)(ws + 16384);             // 5184 f
    float*  bnscale = (float*)(ws + 40960);             // 256 f
    float*  bnshift = (float*)(ws + 45056);             // 256 f
    __bf16* xT      = (__bf16*)(ws + 49152);            // 33.5 MB
    __bf16* rwq     = (__bf16*)(ws + 49152 + 33554432); // 18.9 MB

    hipMemsetAsync(pooled, 0, 4096 * sizeof(float), stream);
    transpose_pool_kernel<<<dim3(64, 16), 256, 0, stream>>>(x, xT, pooled);
    routing_kernel<<<1, 256, 0, stream>>>(pooled, w_lambda, w_theta,
                                          bn_gamma, bn_beta, bn_mean, bn_var,
                                          S, bnscale, bnshift);
    rotw_kernel<<<256, 256, 0, stream>>>(weight, S, rwq);
    conv_kernel<<<dim3(8, 4, 16), 256, 0, stream>>>(xT, rwq, bnscale, bnshift, out);
}

// Round 5
// 271.355 us; speedup vs baseline: 1.3300x; 1.3300x over previous
//
#include <hip/hip_runtime.h>
#include <math.h>

typedef __bf16  bf16x8 __attribute__((ext_vector_type(8)));
typedef float   f32x4  __attribute__((ext_vector_type(4)));

// async global->LDS, 16B per lane. Pass per-lane dest (= base + lane*16).
#define GLD_LDS16(dst, src)                                                      \
    __builtin_amdgcn_global_load_lds(                                            \
        (const __attribute__((address_space(1))) unsigned int*)(src),            \
        (__attribute__((address_space(3))) unsigned int*)(dst), 16, 0, 0)

// ---------------------------------------------------------------------------
// Kernel T: x[b,ci,h,w] fp32 -> xT[b,h,w,ci] bf16 (plain; no fused pool —
// R4 showed the shuffle-chain fusion is latency-bound, 97.8us @ 808 GB/s)
// ---------------------------------------------------------------------------
__global__ __launch_bounds__(256) void transpose_kernel(const float* __restrict__ x,
                                                        __bf16* __restrict__ xT) {
    int h = blockIdx.x, b = blockIdx.y;
    int lane = threadIdx.x & 63, wv = threadIdx.x >> 6;
#pragma unroll
    for (int i = 0; i < 8; i++) {
        int cq = i * 4 + wv;                       // ci octet 0..31
        const float* src = x + (((size_t)(b * 256 + cq * 8) * 64 + h) * 64 + lane);
        bf16x8 o;
#pragma unroll
        for (int j = 0; j < 8; j++) o[j] = (__bf16)src[(size_t)j * 4096];
        *(bf16x8*)(xT + (((size_t)(b * 64 + h) * 64 + lane) * 256 + cq * 8)) = o;
    }
}

// ---------------------------------------------------------------------------
// Kernel A: global average pool (runs after transpose; x is LLC-warm)
// ---------------------------------------------------------------------------
__global__ __launch_bounds__(256) void pool_kernel(const float* __restrict__ x,
                                                   float* __restrict__ pooled) {
    int bc = blockIdx.x;
    const float* p = x + (size_t)bc * 4096;
    int t = threadIdx.x;
    float s = 0.f;
#pragma unroll
    for (int i = 0; i < 16; i++) s += p[t + i * 256];
#pragma unroll
    for (int off = 32; off > 0; off >>= 1) s += __shfl_down(s, off, 64);
    __shared__ float red[4];
    if ((t & 63) == 0) red[t >> 6] = s;
    __syncthreads();
    if (t == 0) pooled[bc] = (red[0] + red[1] + red[2] + red[3]) * (1.f / 4096.f);
}

// ---------------------------------------------------------------------------
// Kernel C: routing (computed redundantly per block) + rotated weights.
// rwq[b][tap][co][ci] bf16. One block per co.
// ---------------------------------------------------------------------------
__global__ __launch_bounds__(256) void rotw_kernel(
    const float* __restrict__ weight, const float* __restrict__ pooled,
    const float* __restrict__ w_lambda, const float* __restrict__ w_theta,
    __bf16* __restrict__ rwq) {
    // sl[b][n][p][12-pad] : lambda*R, rows 16B-aligned for float4 reads
    __shared__ __attribute__((aligned(16))) float sl[16][4][9][12];
    __shared__ float wlds[4][2304];      // [n][ci*9+q]
    int co = blockIdx.x;
    int t = threadIdx.x;
#pragma unroll
    for (int n = 0; n < 4; n++) {
        const float* wp = weight + ((size_t)n * 256 + co) * 2304;
        for (int i = t; i < 2304; i += 256) wlds[n][i] = wp[i];
    }
    if (t < 64) {
        int b = t >> 2, n = t & 3;
        float zl = 0.f, zt = 0.f;
        for (int ci = 0; ci < 256; ci++) {
            float p = pooled[b * 256 + ci];
            zl += p * w_lambda[ci * 4 + n];
            zt += p * w_theta[ci * 4 + n];
        }
        float lam = 1.f / (1.f + expf(-zl));
        float th  = 3.14159265358979323846f * (zt / (1.f + fabsf(zt)));
        float xc = cosf(th), ys = sinf(th);
        float a = xc - ys, bb = xc * ys, c = xc + ys;
        float R[9][9];
#pragma unroll
        for (int i = 0; i < 9; i++)
#pragma unroll
            for (int j = 0; j < 9; j++) R[i][j] = 0.f;
        if (th >= 0.f) {
            R[0][0] = a;       R[0][1] = 1 - a;
            R[1][1] = xc - bb; R[1][2] = bb;       R[1][4] = 1 - c + bb; R[1][5] = ys - bb;
            R[2][2] = a;       R[2][5] = 1 - a;
            R[3][0] = bb;      R[3][1] = ys - bb;  R[3][3] = xc - bb;    R[3][4] = 1 - c + bb;
            R[4][4] = 1.f;
            R[5][4] = 1 - c + bb; R[5][5] = xc - bb; R[5][7] = ys - bb;  R[5][8] = bb;
            R[6][3] = 1 - a;   R[6][6] = a;
            R[7][3] = ys - bb; R[7][4] = 1 - c + bb; R[7][6] = bb;       R[7][7] = xc - bb;
            R[8][7] = 1 - a;   R[8][8] = a;
        } else {
            R[0][0] = c;       R[0][3] = 1 - c;
            R[1][0] = -bb;     R[1][1] = xc + bb;  R[1][3] = bb - ys;    R[1][4] = 1 - a - bb;
            R[2][1] = 1 - c;   R[2][2] = c;
            R[3][3] = xc + bb; R[3][4] = 1 - a - bb; R[3][6] = -bb;      R[3][7] = bb - ys;
            R[4][4] = 1.f;
            R[5][1] = bb - ys; R[5][2] = -bb;      R[5][4] = 1 - a - bb; R[5][5] = xc + bb;
            R[6][6] = c;       R[6][7] = 1 - c;
            R[7][4] = 1 - a - bb; R[7][5] = bb - ys; R[7][7] = xc + bb;  R[7][8] = -bb;
            R[8][5] = 1 - c;   R[8][8] = c;
        }
#pragma unroll
        for (int p = 0; p < 9; p++) {
#pragma unroll
            for (int q = 0; q < 9; q++) sl[b][n][p][q] = lam * R[p][q];
            sl[b][n][p][9] = sl[b][n][p][10] = sl[b][n][p][11] = 0.f;
        }
    }
    __syncthreads();
    int ci = t;
    float4 wa[4], wb[4];
    float  wc[4];
#pragma unroll
    for (int n = 0; n < 4; n++) {
        const float* wp = &wlds[n][ci * 9];
        wa[n] = make_float4(wp[0], wp[1], wp[2], wp[3]);
        wb[n] = make_float4(wp[4], wp[5], wp[6], wp[7]);
        wc[n] = wp[8];
    }
    for (int b = 0; b < 16; b++) {
#pragma unroll
        for (int p = 0; p < 9; p++) {
            float s = 0.f;
#pragma unroll
            for (int n = 0; n < 4; n++) {
                float4 sa = *(const float4*)&sl[b][n][p][0];
                float4 sb = *(const float4*)&sl[b][n][p][4];
                float  sc = sl[b][n][p][8];
                s += sa.x * wa[n].x + sa.y * wa[n].y + sa.z * wa[n].z + sa.w * wa[n].w
                   + sb.x * wb[n].x + sb.y * wb[n].y + sb.z * wb[n].z + sb.w * wb[n].w
                   + sc * wc[n];
            }
            rwq[(((size_t)b * 9 + p) * 256 + co) * 256 + ci] = (__bf16)s;
        }
    }
}

// ---------------------------------------------------------------------------
// Kernel D: implicit-GEMM conv + fused BN/ReLU.
// XCD-aware 1D grid (512): r=lin&7 -> XCD class; class r owns b in {2r,2r+1},
// processed b-sequential so per-b working set (xT 2.1MB + rwq 1.2MB) stays in
// that XCD's 4MB L2 -> weights/x fetched ~once from HBM.
// Tile: b, 64 co, 8 rows; 2 barriers per 32-ci chunk; all-tap weight staging.
// ---------------------------------------------------------------------------
__global__ __launch_bounds__(256, 2) void conv_kernel(
    const __bf16* __restrict__ xT, const __bf16* __restrict__ rwq,
    const float* __restrict__ bn_gamma, const float* __restrict__ bn_beta,
    const float* __restrict__ bn_mean,  const float* __restrict__ bn_var,
    float* __restrict__ out) {
    __shared__ __attribute__((aligned(16))) __bf16 xs[10][4][66][8];
    __shared__ __attribute__((aligned(16))) __bf16 as9[9][4][66][8];
    __shared__ float bns[64], bnh[64];

    const int t    = threadIdx.x;
    const int lane = t & 63;
    const int wv   = t >> 6;
    const int l15  = lane & 15;
    const int kq4  = lane >> 4;

    const int lin  = blockIdx.x;
    const int r    = lin & 7;
    const int k    = lin >> 3;
    const int b    = (r << 1) | (k >> 5);
    const int inner = k & 31;
    const int co0  = (inner & 3) << 6;
    const int h0   = (inner >> 2) << 3;

    if (t < 64) {
        float inv = rsqrtf(bn_var[co0 + t] + 1e-5f);
        float sc = bn_gamma[co0 + t] * inv;
        bns[t] = sc;
        bnh[t] = bn_beta[co0 + t] - bn_mean[co0 + t] * sc;
    }

    f32x4 acc[2][4][4];
#pragma unroll
    for (int rr = 0; rr < 2; rr++)
#pragma unroll
        for (int m = 0; m < 4; m++)
#pragma unroll
            for (int n = 0; n < 4; n++) acc[rr][m][n] = (f32x4){0.f, 0.f, 0.f, 0.f};

    const uint4 zero4 = {0u, 0u, 0u, 0u};
    if (t < 40) {
        int rr = t >> 2, kq = t & 3;
        *(uint4*)&xs[rr][kq][0][0]  = zero4;
        *(uint4*)&xs[rr][kq][65][0] = zero4;
    }

    for (int ci0 = 0; ci0 < 256; ci0 += 32) {
        __syncthreads();                 // prev chunk's compute done before overwrite
        // stage x: 40 units (rr 0..9, kq 0..3); 10 per wave; lane = w
#pragma unroll
        for (int u = wv * 10; u < wv * 10 + 10; u++) {
            int rr = u >> 2, kq = u & 3;
            int hh = h0 - 1 + rr;
            if (hh >= 0 && hh < 64) {
                const __bf16* src = xT + (((size_t)(b * 64 + hh) * 64 + lane) * 256 + ci0 + kq * 8);
                GLD_LDS16(&xs[rr][kq][1 + lane][0], src);
            } else {
                *(uint4*)&xs[rr][kq][1 + lane][0] = zero4;
            }
        }
        // stage weights, all 9 taps: 36 units (tap, kq); 9 per wave; lane = co
#pragma unroll
        for (int u = wv * 9; u < wv * 9 + 9; u++) {
            int tap = u >> 2, kq = u & 3;
            const __bf16* src = rwq +
                ((((size_t)b * 9 + tap) * 256 + co0 + lane) * 256 + ci0 + kq * 8);
            GLD_LDS16(&as9[tap][kq][lane][0], src);
        }
        __syncthreads();                 // drains DMA; xs + as9 ready
#pragma unroll
        for (int tap = 0; tap < 9; tap++) {
            const int dh = tap / 3, dw = tap % 3;
            bf16x8 af[4];
#pragma unroll
            for (int m = 0; m < 4; m++)
                af[m] = *(const bf16x8*)&as9[tap][kq4][m * 16 + l15][0];
#pragma unroll
            for (int rr = 0; rr < 2; rr++) {
                const int hl = wv + rr * 4;
#pragma unroll
                for (int nt = 0; nt < 4; nt++) {
                    bf16x8 bfr = *(const bf16x8*)&xs[hl + dh][kq4][nt * 16 + l15 + dw][0];
#pragma unroll
                    for (int m = 0; m < 4; m++)
                        acc[rr][m][nt] = __builtin_amdgcn_mfma_f32_16x16x32_bf16(
                            af[m], bfr, acc[rr][m][nt], 0, 0, 0);
                }
            }
        }
    }

    // epilogue: BN + ReLU. D layout: row(co) = kq4*4+reg, col(w) = l15
#pragma unroll
    for (int rr = 0; rr < 2; rr++) {
        const int h = h0 + wv + rr * 4;
#pragma unroll
        for (int m = 0; m < 4; m++) {
#pragma unroll
            for (int reg = 0; reg < 4; reg++) {
                int col = m * 16 + kq4 * 4 + reg;        // local co 0..63
                float sc = bns[col], sh = bnh[col];
                int co = co0 + col;
#pragma unroll
                for (int nt = 0; nt < 4; nt++) {
                    int w = nt * 16 + l15;
                    float v = acc[rr][m][nt][reg] * sc + sh;
                    out[(((size_t)b * 256 + co) * 64 + h) * 64 + w] = v > 0.f ? v : 0.f;
                }
            }
        }
    }
}

// ---------------------------------------------------------------------------
extern "C" void kernel_launch(void* const* d_in, const int* in_sizes, int n_in,
                              void* d_out, int out_size, void* d_ws, size_t ws_size,
                              hipStream_t stream) {
    const float* x        = (const float*)d_in[0];
    const float* weight   = (const float*)d_in[1];
    const float* w_lambda = (const float*)d_in[2];
    const float* w_theta  = (const float*)d_in[3];
    const float* bn_gamma = (const float*)d_in[4];
    const float* bn_beta  = (const float*)d_in[5];
    const float* bn_mean  = (const float*)d_in[6];
    const float* bn_var   = (const float*)d_in[7];
    float* out = (float*)d_out;

    char* ws = (char*)d_ws;
    float*  pooled  = (float*)(ws);                     // 4096 f
    __bf16* xT      = (__bf16*)(ws + 49152);            // 33.5 MB
    __bf16* rwq     = (__bf16*)(ws + 49152 + 33554432); // 18.9 MB

    transpose_kernel<<<dim3(64, 16), 256, 0, stream>>>(x, xT);
    pool_kernel<<<4096, 256, 0, stream>>>(x, pooled);
    rotw_kernel<<<256, 256, 0, stream>>>(weight, pooled, w_lambda, w_theta, rwq);
    conv_kernel<<<512, 256, 0, stream>>>(xT, rwq,
                                         bn_gamma, bn_beta, bn_mean, bn_var, out);
}